// Round 8
// baseline (167.768 us; speedup 1.0000x reference)
//
#include <hip/hip_runtime.h>
#include <stdint.h>
#include <math.h>

constexpr int NB = 8;
constexpr int NC = 32;
constexpr int NK = 512;
constexpr int ROWS = 2;          // rows (i) per filter block

struct alignas(16) Entry { uint32_t tag; uint32_t pad; double D; };

// ---------------------------------------------------------------------------
// Threefry2x32 (Random123 / JAX), key = (0, 42), x0 = 0 (flat idx < 2^32)
// partitionable mode: bits(n) = o0 ^ o1            (verbatim R1-R7, proven)
// ---------------------------------------------------------------------------
__device__ __forceinline__ uint32_t rotl32(uint32_t x, uint32_t r) {
    return (x << r) | (x >> (32u - r));
}

__device__ __forceinline__ uint32_t jax_random_bits(uint32_t n) {
    const uint32_t k0 = 0u, k1 = 42u;
    const uint32_t ks2 = k0 ^ k1 ^ 0x1BD11BDAu;
    uint32_t x0 = 0u + k0, x1 = n + k1;

    x0 += x1; x1 = rotl32(x1, 13); x1 ^= x0;
    x0 += x1; x1 = rotl32(x1, 15); x1 ^= x0;
    x0 += x1; x1 = rotl32(x1, 26); x1 ^= x0;
    x0 += x1; x1 = rotl32(x1,  6); x1 ^= x0;
    x0 += k1; x1 += ks2 + 1u;

    x0 += x1; x1 = rotl32(x1, 17); x1 ^= x0;
    x0 += x1; x1 = rotl32(x1, 29); x1 ^= x0;
    x0 += x1; x1 = rotl32(x1, 16); x1 ^= x0;
    x0 += x1; x1 = rotl32(x1, 24); x1 ^= x0;
    x0 += ks2; x1 += k0 + 2u;

    x0 += x1; x1 = rotl32(x1, 13); x1 ^= x0;
    x0 += x1; x1 = rotl32(x1, 15); x1 ^= x0;
    x0 += x1; x1 = rotl32(x1, 26); x1 ^= x0;
    x0 += x1; x1 = rotl32(x1,  6); x1 ^= x0;
    x0 += k0; x1 += k1 + 3u;

    x0 += x1; x1 = rotl32(x1, 17); x1 ^= x0;
    x0 += x1; x1 = rotl32(x1, 29); x1 ^= x0;
    x0 += x1; x1 = rotl32(x1, 16); x1 ^= x0;
    x0 += x1; x1 = rotl32(x1, 24); x1 ^= x0;
    x0 += k1; x1 += ks2 + 4u;

    x0 += x1; x1 = rotl32(x1, 13); x1 ^= x0;
    x0 += x1; x1 = rotl32(x1, 15); x1 ^= x0;
    x0 += x1; x1 = rotl32(x1, 26); x1 ^= x0;
    x0 += x1; x1 = rotl32(x1,  6); x1 ^= x0;
    x0 += ks2; x1 += k0 + 5u;

    return x0 ^ x1;
}

// u (f64, JAX-exact) and fast f32 L = -log(u).     (verbatim R2-R7, proven)
__device__ __forceinline__ float fastL(uint32_t bits, double& ud) {
    const double S = 1.0 - 1e-10, T = 1e-10;
    uint32_t fb = (bits >> 9) | 0x3F800000u;
    float bf = __uint_as_float(fb) - 1.0f;            // exact 23-bit uniform [0,1)
    ud = (double)bf * S + T;                          // >= 1e-10 by construction
    if (bf <= 0.5f) {
        return -logf((float)ud);
    } else {
        double vm1 = S * ((double)bf - 1.0);          // u-1 in f64 (no cancel loss)
        return -log1pf((float)vm1);
    }
}

// rare exact-path fallback                          (verbatim, proven)
__device__ __noinline__ bool decide_slow(double a2, double c2,
                                         double u0, double u1) {
    return a2 * (-log(u1)) >= c2 * (-log(u0));
}

// ---------------------------------------------------------------------------
// Prep: zero out (262144 f32 == grid), F = wa*amp+wp*ph (f64, ws),
// A2[j] = A_jj^2, zero the worklist counter.  grid 1024 x 256.
// ---------------------------------------------------------------------------
__global__ void prep_kernel(const float* __restrict__ amp,
                            const float* __restrict__ ph,
                            const float* __restrict__ A,
                            const float* __restrict__ wav,
                            const float* __restrict__ wpv,
                            double* __restrict__ F,
                            double* __restrict__ A2,
                            uint32_t* __restrict__ cnt,
                            float* __restrict__ out) {
    int t = blockIdx.x * 256 + threadIdx.x;
    out[t] = 0.0f;
    if (t < NB * NC * NK) {
        double wa = (double)wav[0], wp = (double)wpv[0];
        F[t] = wa * (double)amp[t] + wp * (double)ph[t];
    }
    if (t < NK) {
        double a = (double)A[t * NK + t];
        A2[t] = a * a;
    }
    if (t == 0) *cnt = 0;        // ws is re-poisoned each launch: must re-zero
}

// ---------------------------------------------------------------------------
// Phase A: dist + row-min q (global qarr) + stage-1 filter; survivors appended
// to a global worklist (one device-scope atomicAdd per wave).
// grid (NK/ROWS, NB) x 256; thread owns cols j = 2*tid, 2*tid+1.
// ---------------------------------------------------------------------------
__global__ __launch_bounds__(256) void filter_kernel(
    const double* __restrict__ F, const double* __restrict__ A2,
    double* __restrict__ qarr, uint32_t* __restrict__ cnt,
    Entry* __restrict__ list)
{
    const int i0   = blockIdx.x * ROWS;
    const int b    = blockIdx.y;
    const int tid  = threadIdx.x;
    const int j0   = 2 * tid;
    const int lane = tid & 63;
    const int wv   = tid >> 6;

    __shared__ double sred[ROWS][4];
    __shared__ double s_q[ROWS];

    const double* __restrict__ Fb = F + (size_t)b * NC * NK;

    // ---- dist accumulation (same per-element fma chain as R1-R7)
    double acc[2][ROWS];
    #pragma unroll
    for (int it = 0; it < 2; ++it)
        #pragma unroll
        for (int r = 0; r < ROWS; ++r) acc[it][r] = 0.0;

    #pragma unroll 8
    for (int c = 0; c < NC; ++c) {
        double fr0 = Fb[c * NK + i0];         // uniform -> scalar loads
        double fr1 = Fb[c * NK + i0 + 1];
        double2 fj = *(const double2*)(Fb + c * NK + j0);   // 16B coalesced
        double d00 = fr0 - fj.x; acc[0][0] = fma(d00, d00, acc[0][0]);
        double d10 = fr0 - fj.y; acc[1][0] = fma(d10, d10, acc[1][0]);
        double d01 = fr1 - fj.x; acc[0][1] = fma(d01, d01, acc[0][1]);
        double d11 = fr1 - fj.y; acc[1][1] = fma(d11, d11, acc[1][1]);
    }

    double2 a2j = *(const double2*)(A2 + j0);
    double D[2][ROWS];
    #pragma unroll
    for (int r = 0; r < ROWS; ++r) {
        D[0][r] = acc[0][r] * a2j.x + 1e-10;   // same rounding as R1-R7
        D[1][r] = acc[1][r] * a2j.y + 1e-10;
    }

    // per-row min over j != i (exact, order-independent; proven path)
    #pragma unroll
    for (int r = 0; r < ROWS; ++r) {
        const int i = i0 + r;
        double m = 1e300;
        if (j0     != i) m = fmin(m, D[0][r]);
        if (j0 + 1 != i) m = fmin(m, D[1][r]);
        #pragma unroll
        for (int off = 32; off > 0; off >>= 1)
            m = fmin(m, __shfl_down(m, off));
        if (lane == 0) sred[r][wv] = m;
    }
    __syncthreads();
    if (tid < ROWS) {
        double m = fmin(fmin(sred[tid][0], sred[tid][1]),
                        fmin(sred[tid][2], sred[tid][3]));
        double qv = 0.99 * m;
        s_q[tid] = qv;
        qarr[b * NK + i0 + tid] = qv;          // for decide_kernel
    }
    __syncthreads();

    // ---- stage-1 deterministic-false filter + global append.
    // Skip iff (D-q)^2 > 1.95e8*q^2 (false for ANY draw; 1% log-margin, f64).
    const unsigned long long ltmask = (1ull << lane) - 1ull;
    bool need[2][ROWS];
    #pragma unroll
    for (int r = 0; r < ROWS; ++r) {
        const int i = i0 + r;
        const double q = s_q[r];
        const double thr = 1.95e8 * (q * q);
        double t0 = D[0][r] - q;
        double t1 = D[1][r] - q;
        need[0][r] = (j0     == i) || !(t0 * t0 > thr);
        need[1][r] = (j0 + 1 == i) || !(t1 * t1 > thr);
    }
    unsigned long long m00 = __ballot(need[0][0]);
    unsigned long long m10 = __ballot(need[1][0]);
    unsigned long long m01 = __ballot(need[0][1]);
    unsigned long long m11 = __ballot(need[1][1]);
    int c00 = __popcll(m00), c10 = __popcll(m10);
    int c01 = __popcll(m01), c11 = __popcll(m11);
    int total = c00 + c10 + c01 + c11;

    int base = 0;
    if (lane == 0) base = (int)atomicAdd(cnt, (uint32_t)total);  // device scope
    base = __shfl(base, 0);

    const uint32_t rowtag0 = (uint32_t)(b * NK + i0) << 9;
    const uint32_t rowtag1 = (uint32_t)(b * NK + i0 + 1) << 9;
    if (need[0][0]) {
        Entry e{rowtag0 | (uint32_t)j0, 0u, D[0][0]};
        list[base + __popcll(m00 & ltmask)] = e;
    }
    if (need[1][0]) {
        Entry e{rowtag0 | (uint32_t)(j0 + 1), 0u, D[1][0]};
        list[base + c00 + __popcll(m10 & ltmask)] = e;
    }
    const int base2 = base + c00 + c10;
    if (need[0][1]) {
        Entry e{rowtag1 | (uint32_t)j0, 0u, D[0][1]};
        list[base2 + __popcll(m01 & ltmask)] = e;
    }
    if (need[1][1]) {
        Entry e{rowtag1 | (uint32_t)(j0 + 1), 0u, D[1][1]};
        list[base2 + c01 + __popcll(m11 & ltmask)] = e;
    }
}

// ---------------------------------------------------------------------------
// Phase B: dense staged-RNG decisions over the worklist (grid-stride).
// ---------------------------------------------------------------------------
__global__ __launch_bounds__(256) void decide_kernel(
    const Entry* __restrict__ list, const uint32_t* __restrict__ cnt,
    const double* __restrict__ qarr, float* __restrict__ out)
{
    const int n = (int)*cnt;
    for (int k = blockIdx.x * 256 + threadIdx.x; k < n; k += gridDim.x * 256) {
        Entry e = list[k];
        const uint32_t tag = e.tag;
        const int j   = (int)(tag & 511u);
        const int row = (int)(tag >> 9);       // b*NK + i
        const int i   = row & 511;
        const double Dv = e.D;
        const double q  = qarr[row];

        double a2, c2;
        if (j == i) { a2 = 9801.0; c2 = 1.0; }
        else        { a2 = q * q; double t = Dv - q; c2 = t * t; }

        const uint32_t n0 = 2u * ((uint32_t)row * (uint32_t)NK + (uint32_t)j);
        bool hit = false;
        uint32_t bits0 = jax_random_bits(n0);
        double u0d;
        float L0f = fastL(bits0, u0d);
        float L0lo = L0f * 0.99999f;
        // stage-2 conservative skip: provably false for any u1
        // (L1 <= -ln(1e-10) = 23.0258509...; margin >= 1.5e-4 rel)
        if (!((double)c2 * (double)L0lo > 23.03 * a2)) {
            uint32_t bits1 = jax_random_bits(n0 + 1u);
            double u1d;
            float L1f = fastL(bits1, u1d);
            float lhs = (float)a2 * L1f;
            float rhs = (float)c2 * L0f;
            float diff = lhs - rhs;
            if (fabsf(diff) > 1e-4f * (lhs + rhs))
                hit = diff >= 0.0f;               // fast path, sign-safe
            else
                hit = decide_slow(a2, c2, u0d, u1d);
        }
        if (hit)
            atomicAdd(&out[i * NK + j], 0.125f);  // mean over B=8, exact
    }
}

extern "C" void kernel_launch(void* const* d_in, const int* in_sizes, int n_in,
                              void* d_out, int out_size, void* d_ws, size_t ws_size,
                              hipStream_t stream) {
    const float* amp = (const float*)d_in[0];   // (8,32,512)
    const float* ph  = (const float*)d_in[1];   // (8,32,512)
    const float* A   = (const float*)d_in[2];   // (512,512)
    const float* wa  = (const float*)d_in[3];   // scalar
    const float* wp  = (const float*)d_in[4];   // scalar
    float* out = (float*)d_out;                 // (512,512) f32

    // ws layout (f64 units): F[131072] | A2[512] | qarr[4096] | cnt | list
    double*   F    = (double*)d_ws;
    double*   A2   = F + NB * NC * NK;
    double*   qarr = A2 + NK;
    uint32_t* cnt  = (uint32_t*)(qarr + NB * NK);
    Entry*    list = (Entry*)((char*)d_ws +
                       ((size_t)(NB * NC * NK + NK + NB * NK) * 8 + 16));
    // capacity: worst case 2,097,152 entries * 16 B = 33.6 MB << ws (256 MiB)

    prep_kernel<<<1024, 256, 0, stream>>>(amp, ph, A, wa, wp, F, A2, cnt, out);

    dim3 grid(NK / ROWS, NB);
    filter_kernel<<<grid, 256, 0, stream>>>(F, A2, qarr, cnt, list);

    decide_kernel<<<2048, 256, 0, stream>>>(list, cnt, qarr, out);
}

// Round 9
// 82.158 us; speedup vs baseline: 2.0420x; 2.0420x over previous
//
#include <hip/hip_runtime.h>
#include <stdint.h>
#include <math.h>

constexpr int NB = 8;
constexpr int NC = 32;
constexpr int NK = 512;
constexpr int ROWS = 4;          // rows (i) per filter block
constexpr int SLOT = 512;        // max survivors per wave = 2 cols * ROWS * 64

struct alignas(16) Entry { uint32_t tag; uint32_t pad; double D; };

// ---------------------------------------------------------------------------
// Threefry2x32 (Random123 / JAX), key = (0, 42), x0 = 0 (flat idx < 2^32)
// partitionable mode: bits(n) = o0 ^ o1            (verbatim R1-R8, proven)
// ---------------------------------------------------------------------------
__device__ __forceinline__ uint32_t rotl32(uint32_t x, uint32_t r) {
    return (x << r) | (x >> (32u - r));
}

__device__ __forceinline__ uint32_t jax_random_bits(uint32_t n) {
    const uint32_t k0 = 0u, k1 = 42u;
    const uint32_t ks2 = k0 ^ k1 ^ 0x1BD11BDAu;
    uint32_t x0 = 0u + k0, x1 = n + k1;

    x0 += x1; x1 = rotl32(x1, 13); x1 ^= x0;
    x0 += x1; x1 = rotl32(x1, 15); x1 ^= x0;
    x0 += x1; x1 = rotl32(x1, 26); x1 ^= x0;
    x0 += x1; x1 = rotl32(x1,  6); x1 ^= x0;
    x0 += k1; x1 += ks2 + 1u;

    x0 += x1; x1 = rotl32(x1, 17); x1 ^= x0;
    x0 += x1; x1 = rotl32(x1, 29); x1 ^= x0;
    x0 += x1; x1 = rotl32(x1, 16); x1 ^= x0;
    x0 += x1; x1 = rotl32(x1, 24); x1 ^= x0;
    x0 += ks2; x1 += k0 + 2u;

    x0 += x1; x1 = rotl32(x1, 13); x1 ^= x0;
    x0 += x1; x1 = rotl32(x1, 15); x1 ^= x0;
    x0 += x1; x1 = rotl32(x1, 26); x1 ^= x0;
    x0 += x1; x1 = rotl32(x1,  6); x1 ^= x0;
    x0 += k0; x1 += k1 + 3u;

    x0 += x1; x1 = rotl32(x1, 17); x1 ^= x0;
    x0 += x1; x1 = rotl32(x1, 29); x1 ^= x0;
    x0 += x1; x1 = rotl32(x1, 16); x1 ^= x0;
    x0 += x1; x1 = rotl32(x1, 24); x1 ^= x0;
    x0 += k1; x1 += ks2 + 4u;

    x0 += x1; x1 = rotl32(x1, 13); x1 ^= x0;
    x0 += x1; x1 = rotl32(x1, 15); x1 ^= x0;
    x0 += x1; x1 = rotl32(x1, 26); x1 ^= x0;
    x0 += x1; x1 = rotl32(x1,  6); x1 ^= x0;
    x0 += ks2; x1 += k0 + 5u;

    return x0 ^ x1;
}

// u (f64, JAX-exact) and fast f32 L = -log(u).     (verbatim, proven)
__device__ __forceinline__ float fastL(uint32_t bits, double& ud) {
    const double S = 1.0 - 1e-10, T = 1e-10;
    uint32_t fb = (bits >> 9) | 0x3F800000u;
    float bf = __uint_as_float(fb) - 1.0f;            // exact 23-bit uniform [0,1)
    ud = (double)bf * S + T;                          // >= 1e-10 by construction
    if (bf <= 0.5f) {
        return -logf((float)ud);
    } else {
        double vm1 = S * ((double)bf - 1.0);          // u-1 in f64 (no cancel loss)
        return -log1pf((float)vm1);
    }
}

// rare exact-path fallback                          (verbatim, proven)
__device__ __noinline__ bool decide_slow(double a2, double c2,
                                         double u0, double u1) {
    return a2 * (-log(u1)) >= c2 * (-log(u0));
}

// ---------------------------------------------------------------------------
// Prep: zero out (262144 f32 == grid), F = wa*amp+wp*ph (f64, ws),
// A2[j] = A_jj^2.  grid 1024 x 256.  (no global counter anymore)
// ---------------------------------------------------------------------------
__global__ void prep_kernel(const float* __restrict__ amp,
                            const float* __restrict__ ph,
                            const float* __restrict__ A,
                            const float* __restrict__ wav,
                            const float* __restrict__ wpv,
                            double* __restrict__ F,
                            double* __restrict__ A2,
                            float* __restrict__ out) {
    int t = blockIdx.x * 256 + threadIdx.x;
    out[t] = 0.0f;
    if (t < NB * NC * NK) {
        double wa = (double)wav[0], wp = (double)wpv[0];
        F[t] = wa * (double)amp[t] + wp * (double)ph[t];
    }
    if (t < NK) {
        double a = (double)A[t * NK + t];
        A2[t] = a * a;
    }
}

// ---------------------------------------------------------------------------
// Phase A: dist + row-min q (global qarr) + stage-1 filter; survivors written
// to the wave's OWN fixed slot (no atomics of any kind, no cross-wave state).
// grid (NK/ROWS, NB) x 256; thread owns cols j = 2*tid, 2*tid+1.
// ---------------------------------------------------------------------------
__global__ __launch_bounds__(256) void filter_kernel(
    const double* __restrict__ F, const double* __restrict__ A2,
    double* __restrict__ qarr, uint32_t* __restrict__ counts,
    Entry* __restrict__ list)
{
    const int i0   = blockIdx.x * ROWS;
    const int b    = blockIdx.y;
    const int tid  = threadIdx.x;
    const int j0   = 2 * tid;
    const int lane = tid & 63;
    const int wv   = tid >> 6;
    const int wid  = ((b * gridDim.x) + blockIdx.x) * 4 + wv;   // 0..4095
    Entry* __restrict__ slot = list + (size_t)wid * SLOT;

    __shared__ double sred[ROWS][4];
    __shared__ double s_q[ROWS];

    const double* __restrict__ Fb = F + (size_t)b * NC * NK;

    // ---- dist accumulation (same per-element fma chain as R1-R8)
    double acc[2][ROWS];
    #pragma unroll
    for (int it = 0; it < 2; ++it)
        #pragma unroll
        for (int r = 0; r < ROWS; ++r) acc[it][r] = 0.0;

    #pragma unroll 8
    for (int c = 0; c < NC; ++c) {
        double fi_r[ROWS];
        #pragma unroll
        for (int r = 0; r < ROWS; ++r)
            fi_r[r] = Fb[c * NK + i0 + r];          // uniform -> scalar loads
        double2 fj = *(const double2*)(Fb + c * NK + j0);   // 16B coalesced
        #pragma unroll
        for (int r = 0; r < ROWS; ++r) {
            double d0 = fi_r[r] - fj.x; acc[0][r] = fma(d0, d0, acc[0][r]);
            double d1 = fi_r[r] - fj.y; acc[1][r] = fma(d1, d1, acc[1][r]);
        }
    }

    double2 a2j = *(const double2*)(A2 + j0);
    double D[2][ROWS];
    #pragma unroll
    for (int r = 0; r < ROWS; ++r) {
        D[0][r] = acc[0][r] * a2j.x + 1e-10;   // same rounding as R1-R8
        D[1][r] = acc[1][r] * a2j.y + 1e-10;
    }

    // per-row min over j != i (exact, order-independent; proven path)
    #pragma unroll
    for (int r = 0; r < ROWS; ++r) {
        const int i = i0 + r;
        double m = 1e300;
        if (j0     != i) m = fmin(m, D[0][r]);
        if (j0 + 1 != i) m = fmin(m, D[1][r]);
        #pragma unroll
        for (int off = 32; off > 0; off >>= 1)
            m = fmin(m, __shfl_down(m, off));
        if (lane == 0) sred[r][wv] = m;
    }
    __syncthreads();
    if (tid < ROWS) {
        double m = fmin(fmin(sred[tid][0], sred[tid][1]),
                        fmin(sred[tid][2], sred[tid][3]));
        double qv = 0.99 * m;
        s_q[tid] = qv;
        qarr[b * NK + i0 + tid] = qv;          // for decide_kernel
    }
    __syncthreads();

    // ---- stage-1 deterministic-false filter + wave-slot append (R7 logic,
    // global instead of LDS). Skip iff (D-q)^2 > 1.95e8*q^2 (false for ANY
    // draw; 1% log-margin, exact f64).
    const unsigned long long ltmask = (1ull << lane) - 1ull;
    int nb = 0;                                  // wave-uniform running count
    #pragma unroll
    for (int r = 0; r < ROWS; ++r) {
        const int i = i0 + r;
        const double q = s_q[r];
        const double thr = 1.95e8 * (q * q);
        double t0 = D[0][r] - q;
        double t1 = D[1][r] - q;
        bool need0 = (j0     == i) || !(t0 * t0 > thr);
        bool need1 = (j0 + 1 == i) || !(t1 * t1 > thr);
        unsigned long long m0 = __ballot(need0);
        unsigned long long m1 = __ballot(need1);
        int c0 = __popcll(m0);
        const uint32_t rowtag = (uint32_t)(b * NK + i) << 9;
        if (need0) {
            Entry e{rowtag | (uint32_t)j0, 0u, D[0][r]};
            slot[nb + __popcll(m0 & ltmask)] = e;
        }
        if (need1) {
            Entry e{rowtag | (uint32_t)(j0 + 1), 0u, D[1][r]};
            slot[nb + c0 + __popcll(m1 & ltmask)] = e;
        }
        nb += c0 + __popcll(m1);
    }
    if (lane == 0) counts[wid] = (uint32_t)nb;   // plain store, no RMW
}

// ---------------------------------------------------------------------------
// Phase B: dense staged-RNG decisions. Wave w of block s owns slot 4s+w.
// grid 1024 x 256 (4096 waves == 4096 slots). No cross-wave state.
// ---------------------------------------------------------------------------
__global__ __launch_bounds__(256) void decide_kernel(
    const Entry* __restrict__ list, const uint32_t* __restrict__ counts,
    const double* __restrict__ qarr, float* __restrict__ out)
{
    const int lane = threadIdx.x & 63;
    const int wv   = threadIdx.x >> 6;
    const int wid  = blockIdx.x * 4 + wv;
    const Entry* __restrict__ slot = list + (size_t)wid * SLOT;
    const int n = (int)counts[wid];

    for (int k = lane; k < n; k += 64) {
        Entry e = slot[k];
        const uint32_t tag = e.tag;
        const int j   = (int)(tag & 511u);
        const int row = (int)(tag >> 9);       // b*NK + i
        const int i   = row & 511;
        const double Dv = e.D;
        const double q  = qarr[row];

        double a2, c2;
        if (j == i) { a2 = 9801.0; c2 = 1.0; }
        else        { a2 = q * q; double t = Dv - q; c2 = t * t; }

        const uint32_t n0 = 2u * ((uint32_t)row * (uint32_t)NK + (uint32_t)j);
        bool hit = false;
        uint32_t bits0 = jax_random_bits(n0);
        double u0d;
        float L0f = fastL(bits0, u0d);
        float L0lo = L0f * 0.99999f;
        // stage-2 conservative skip: provably false for any u1
        // (L1 <= -ln(1e-10) = 23.0258509...; margin >= 1.5e-4 rel)
        if (!((double)c2 * (double)L0lo > 23.03 * a2)) {
            uint32_t bits1 = jax_random_bits(n0 + 1u);
            double u1d;
            float L1f = fastL(bits1, u1d);
            float lhs = (float)a2 * L1f;
            float rhs = (float)c2 * L0f;
            float diff = lhs - rhs;
            if (fabsf(diff) > 1e-4f * (lhs + rhs))
                hit = diff >= 0.0f;               // fast path, sign-safe
            else
                hit = decide_slow(a2, c2, u0d, u1d);
        }
        if (hit)
            atomicAdd(&out[i * NK + j], 0.125f);  // mean over B=8, exact
    }
}

extern "C" void kernel_launch(void* const* d_in, const int* in_sizes, int n_in,
                              void* d_out, int out_size, void* d_ws, size_t ws_size,
                              hipStream_t stream) {
    const float* amp = (const float*)d_in[0];   // (8,32,512)
    const float* ph  = (const float*)d_in[1];   // (8,32,512)
    const float* A   = (const float*)d_in[2];   // (512,512)
    const float* wa  = (const float*)d_in[3];   // scalar
    const float* wp  = (const float*)d_in[4];   // scalar
    float* out = (float*)d_out;                 // (512,512) f32

    // ws layout (f64 units): F[131072] | A2[512] | qarr[4096] | counts | list
    double*   F      = (double*)d_ws;
    double*   A2     = F + NB * NC * NK;
    double*   qarr   = A2 + NK;
    uint32_t* counts = (uint32_t*)(qarr + NB * NK);          // 4096 u32
    Entry*    list   = (Entry*)((char*)counts + 4096 * sizeof(uint32_t));
    // list: 4096 slots * 512 entries * 16 B = 32 MB << ws (256 MiB)

    prep_kernel<<<1024, 256, 0, stream>>>(amp, ph, A, wa, wp, F, A2, out);

    dim3 grid(NK / ROWS, NB);
    filter_kernel<<<grid, 256, 0, stream>>>(F, A2, qarr, counts, list);

    decide_kernel<<<1024, 256, 0, stream>>>(list, counts, qarr, out);
}

// Round 10
// 80.709 us; speedup vs baseline: 2.0787x; 1.0180x over previous
//
#include <hip/hip_runtime.h>
#include <stdint.h>
#include <math.h>

constexpr int NB = 8;
constexpr int NC = 32;
constexpr int NK = 512;
constexpr int ROWS = 2;          // rows (i) per block

// ---------------------------------------------------------------------------
// Threefry2x32 (Random123 / JAX), key = (0, 42), x0 = 0 (flat idx < 2^32)
// partitionable mode: bits(n) = o0 ^ o1            (verbatim R1-R9, proven)
// ---------------------------------------------------------------------------
__device__ __forceinline__ uint32_t rotl32(uint32_t x, uint32_t r) {
    return (x << r) | (x >> (32u - r));
}

__device__ __forceinline__ uint32_t jax_random_bits(uint32_t n) {
    const uint32_t k0 = 0u, k1 = 42u;
    const uint32_t ks2 = k0 ^ k1 ^ 0x1BD11BDAu;
    uint32_t x0 = 0u + k0, x1 = n + k1;

    x0 += x1; x1 = rotl32(x1, 13); x1 ^= x0;
    x0 += x1; x1 = rotl32(x1, 15); x1 ^= x0;
    x0 += x1; x1 = rotl32(x1, 26); x1 ^= x0;
    x0 += x1; x1 = rotl32(x1,  6); x1 ^= x0;
    x0 += k1; x1 += ks2 + 1u;

    x0 += x1; x1 = rotl32(x1, 17); x1 ^= x0;
    x0 += x1; x1 = rotl32(x1, 29); x1 ^= x0;
    x0 += x1; x1 = rotl32(x1, 16); x1 ^= x0;
    x0 += x1; x1 = rotl32(x1, 24); x1 ^= x0;
    x0 += ks2; x1 += k0 + 2u;

    x0 += x1; x1 = rotl32(x1, 13); x1 ^= x0;
    x0 += x1; x1 = rotl32(x1, 15); x1 ^= x0;
    x0 += x1; x1 = rotl32(x1, 26); x1 ^= x0;
    x0 += x1; x1 = rotl32(x1,  6); x1 ^= x0;
    x0 += k0; x1 += k1 + 3u;

    x0 += x1; x1 = rotl32(x1, 17); x1 ^= x0;
    x0 += x1; x1 = rotl32(x1, 29); x1 ^= x0;
    x0 += x1; x1 = rotl32(x1, 16); x1 ^= x0;
    x0 += x1; x1 = rotl32(x1, 24); x1 ^= x0;
    x0 += k1; x1 += ks2 + 4u;

    x0 += x1; x1 = rotl32(x1, 13); x1 ^= x0;
    x0 += x1; x1 = rotl32(x1, 15); x1 ^= x0;
    x0 += x1; x1 = rotl32(x1, 26); x1 ^= x0;
    x0 += x1; x1 = rotl32(x1,  6); x1 ^= x0;
    x0 += ks2; x1 += k0 + 5u;

    return x0 ^ x1;
}

// u (f64, JAX-exact) and fast f32 L = -log(u).     (verbatim, proven)
__device__ __forceinline__ float fastL(uint32_t bits, double& ud) {
    const double S = 1.0 - 1e-10, T = 1e-10;
    uint32_t fb = (bits >> 9) | 0x3F800000u;
    float bf = __uint_as_float(fb) - 1.0f;            // exact 23-bit uniform [0,1)
    ud = (double)bf * S + T;                          // >= 1e-10 by construction
    if (bf <= 0.5f) {
        return -logf((float)ud);
    } else {
        double vm1 = S * ((double)bf - 1.0);          // u-1 in f64 (no cancel loss)
        return -log1pf((float)vm1);
    }
}

// rare exact-path fallback                          (verbatim, proven)
__device__ __noinline__ bool decide_slow(double a2, double c2,
                                         double u0, double u1) {
    return a2 * (-log(u1)) >= c2 * (-log(u0));
}

// ---------------------------------------------------------------------------
// Prep (R2-R9 proven): zero out (262144 f32 == grid), F = wa*amp+wp*ph (f64,
// ws), A2[j] = A_jj^2.  grid 1024 x 256.
// ---------------------------------------------------------------------------
__global__ void prep_kernel(const float* __restrict__ amp,
                            const float* __restrict__ ph,
                            const float* __restrict__ A,
                            const float* __restrict__ wav,
                            const float* __restrict__ wpv,
                            double* __restrict__ F,
                            double* __restrict__ A2,
                            float* __restrict__ out) {
    int t = blockIdx.x * 256 + threadIdx.x;
    out[t] = 0.0f;
    if (t < NB * NC * NK) {
        double wa = (double)wav[0], wp = (double)wpv[0];
        F[t] = wa * (double)amp[t] + wp * (double)ph[t];
    }
    if (t < NK) {
        double a = (double)A[t * NK + t];
        A2[t] = a * a;
    }
}

// ---------------------------------------------------------------------------
// Fused sample kernel (R7 structure at DOUBLE occupancy): ROWS=2, grid
// (256, 8) = 2048 blocks = 8 blocks/CU = 32 waves/CU. Thread owns cols
// j = 2*tid, 2*tid+1. Wave w owns j in [128w, 128w+128). All compaction
// state WAVE-LOCAL (R5/R7-proven): fused survivor list (entry=(r<<8)|jl),
// wave-private LDS D-mirror, staged RNG in phase 3.
// __launch_bounds__(256, 8): pin >=8 waves/EU => <=64 VGPR.
// ---------------------------------------------------------------------------
__global__ __launch_bounds__(256, 8) void sample_kernel(
    const double* __restrict__ F, const double* __restrict__ A2,
    float* __restrict__ out)
{
    const int i0   = blockIdx.x * ROWS;
    const int b    = blockIdx.y;
    const int tid  = threadIdx.x;
    const int j0   = 2 * tid;
    const int lane = tid & 63;
    const int wv   = tid >> 6;          // wave index 0..3
    const int wjb  = wv * 128;          // wave's j base

    __shared__ double Dsh[4][ROWS][128];            // wave-private D mirror, 8 KB
    __shared__ unsigned short wlist[4][ROWS * 128]; // fused wave lists, 2 KB
    __shared__ double sred[ROWS][4];
    __shared__ double s_q[ROWS];

    const double* __restrict__ Fb = F + (size_t)b * NC * NK;

    // ---- Phase 1: dist accumulation (same per-element fma chain as R1-R9)
    double acc[2][ROWS];
    #pragma unroll
    for (int it = 0; it < 2; ++it)
        #pragma unroll
        for (int r = 0; r < ROWS; ++r) acc[it][r] = 0.0;

    #pragma unroll 8
    for (int c = 0; c < NC; ++c) {
        double fr0 = Fb[c * NK + i0];         // uniform -> scalar loads
        double fr1 = Fb[c * NK + i0 + 1];
        double2 fj = *(const double2*)(Fb + c * NK + j0);   // 16B coalesced
        double d00 = fr0 - fj.x; acc[0][0] = fma(d00, d00, acc[0][0]);
        double d10 = fr0 - fj.y; acc[1][0] = fma(d10, d10, acc[1][0]);
        double d01 = fr1 - fj.x; acc[0][1] = fma(d01, d01, acc[0][1]);
        double d11 = fr1 - fj.y; acc[1][1] = fma(d11, d11, acc[1][1]);
    }

    double2 a2j = *(const double2*)(A2 + j0);
    double D[2][ROWS];
    #pragma unroll
    for (int r = 0; r < ROWS; ++r) {
        D[0][r] = acc[0][r] * a2j.x + 1e-10;   // same rounding as R1-R9
        D[1][r] = acc[1][r] * a2j.y + 1e-10;
        // wave-private mirror for dynamic-(r,jl) access in phase 3
        *(double2*)&Dsh[wv][r][2 * lane] = make_double2(D[0][r], D[1][r]);
    }

    // per-row min over j != i (exact, order-independent; proven path)
    #pragma unroll
    for (int r = 0; r < ROWS; ++r) {
        const int i = i0 + r;
        double m = 1e300;
        if (j0     != i) m = fmin(m, D[0][r]);
        if (j0 + 1 != i) m = fmin(m, D[1][r]);
        #pragma unroll
        for (int off = 32; off > 0; off >>= 1)
            m = fmin(m, __shfl_down(m, off));
        if (lane == 0) sred[r][wv] = m;
    }
    __syncthreads();
    if (tid < ROWS) {
        double m = fmin(fmin(sred[tid][0], sred[tid][1]),
                        fmin(sred[tid][2], sred[tid][3]));
        s_q[tid] = 0.99 * m;
    }
    __syncthreads();

    // ---- Phase 2: stage-1 deterministic-false filter + FUSED wave-local list
    // Skip iff (D-q)^2 > 1.95e8*q^2 (false for ANY draw; 1% log-margin, f64).
    const unsigned long long ltmask = (1ull << lane) - 1ull;
    int nb = 0;                                  // wave-uniform running count
    #pragma unroll
    for (int r = 0; r < ROWS; ++r) {
        const int i = i0 + r;
        const double q = s_q[r];
        const double thr = 1.95e8 * (q * q);
        double t0 = D[0][r] - q;
        double t1 = D[1][r] - q;
        bool need0 = (j0     == i) || !(t0 * t0 > thr);
        bool need1 = (j0 + 1 == i) || !(t1 * t1 > thr);
        unsigned long long m0 = __ballot(need0);
        unsigned long long m1 = __ballot(need1);
        int c0 = __popcll(m0);
        if (need0) wlist[wv][nb + __popcll(m0 & ltmask)] =
            (unsigned short)((r << 8) | (2 * lane));
        if (need1) wlist[wv][nb + c0 + __popcll(m1 & ltmask)] =
            (unsigned short)((r << 8) | (2 * lane + 1));
        nb += c0 + __popcll(m1);
    }
    // same-wave LDS RAW: ordered by program order + lgkmcnt, no barrier needed

    // ---- Phase 3: staged RNG over the fused wave list (R7 verbatim)
    for (int k0v = 0; k0v < nb; k0v += 64) {
        int k = k0v + lane;
        bool act = k < nb;
        int e  = wlist[wv][act ? k : 0];          // in-bounds always
        int r  = e >> 8;
        int jl = e & 255;
        double Dv = Dsh[wv][r][jl];
        double q  = s_q[r];
        const int i = i0 + r;
        const int j = wjb + jl;

        double a2, c2;
        if (j == i) { a2 = 9801.0; c2 = 1.0; }
        else        { a2 = q * q; double t = Dv - q; c2 = t * t; }

        uint32_t n0 = 2u * (((uint32_t)(b * NK + i)) * NK + (uint32_t)j);
        bool hit = false;
        if (act) {
            uint32_t bits0 = jax_random_bits(n0);
            double u0d;
            float L0f = fastL(bits0, u0d);
            float L0lo = L0f * 0.99999f;
            // stage-2 conservative skip: provably false for any u1
            // (L1 <= -ln(1e-10) = 23.0258509...; margin >= 1.5e-4 rel)
            if (!((double)c2 * (double)L0lo > 23.03 * a2)) {
                uint32_t bits1 = jax_random_bits(n0 + 1u);
                double u1d;
                float L1f = fastL(bits1, u1d);
                float lhs = (float)a2 * L1f;
                float rhs = (float)c2 * L0f;
                float diff = lhs - rhs;
                if (fabsf(diff) > 1e-4f * (lhs + rhs))
                    hit = diff >= 0.0f;               // fast path, sign-safe
                else
                    hit = decide_slow(a2, c2, u0d, u1d);
            }
        }
        if (hit)
            atomicAdd(&out[i * NK + j], 0.125f);      // mean over B=8, exact
    }
}

extern "C" void kernel_launch(void* const* d_in, const int* in_sizes, int n_in,
                              void* d_out, int out_size, void* d_ws, size_t ws_size,
                              hipStream_t stream) {
    const float* amp = (const float*)d_in[0];   // (8,32,512)
    const float* ph  = (const float*)d_in[1];   // (8,32,512)
    const float* A   = (const float*)d_in[2];   // (512,512)
    const float* wa  = (const float*)d_in[3];   // scalar
    const float* wp  = (const float*)d_in[4];   // scalar
    float* out = (float*)d_out;                 // (512,512) f32

    double* F  = (double*)d_ws;                    // 131072 f64 = 1 MB
    double* A2 = F + NB * NC * NK;                 // 512 f64

    prep_kernel<<<1024, 256, 0, stream>>>(amp, ph, A, wa, wp, F, A2, out);

    dim3 grid(NK / ROWS, NB);                      // (256, 8) = 2048 blocks
    sample_kernel<<<grid, 256, 0, stream>>>(F, A2, out);
}

// Round 11
// 79.844 us; speedup vs baseline: 2.1012x; 1.0108x over previous
//
#include <hip/hip_runtime.h>
#include <stdint.h>
#include <math.h>

constexpr int NB = 8;
constexpr int NC = 32;
constexpr int NK = 512;
constexpr int ROWS = 4;          // rows (i) per block

// ---------------------------------------------------------------------------
// Threefry2x32 (Random123 / JAX), key = (0, 42), x0 = 0 (flat idx < 2^32)
// partitionable mode: bits(n) = o0 ^ o1            (verbatim R1-R10, proven)
// ---------------------------------------------------------------------------
__device__ __forceinline__ uint32_t rotl32(uint32_t x, uint32_t r) {
    return (x << r) | (x >> (32u - r));
}

__device__ __forceinline__ uint32_t jax_random_bits(uint32_t n) {
    const uint32_t k0 = 0u, k1 = 42u;
    const uint32_t ks2 = k0 ^ k1 ^ 0x1BD11BDAu;
    uint32_t x0 = 0u + k0, x1 = n + k1;

    x0 += x1; x1 = rotl32(x1, 13); x1 ^= x0;
    x0 += x1; x1 = rotl32(x1, 15); x1 ^= x0;
    x0 += x1; x1 = rotl32(x1, 26); x1 ^= x0;
    x0 += x1; x1 = rotl32(x1,  6); x1 ^= x0;
    x0 += k1; x1 += ks2 + 1u;

    x0 += x1; x1 = rotl32(x1, 17); x1 ^= x0;
    x0 += x1; x1 = rotl32(x1, 29); x1 ^= x0;
    x0 += x1; x1 = rotl32(x1, 16); x1 ^= x0;
    x0 += x1; x1 = rotl32(x1, 24); x1 ^= x0;
    x0 += ks2; x1 += k0 + 2u;

    x0 += x1; x1 = rotl32(x1, 13); x1 ^= x0;
    x0 += x1; x1 = rotl32(x1, 15); x1 ^= x0;
    x0 += x1; x1 = rotl32(x1, 26); x1 ^= x0;
    x0 += x1; x1 = rotl32(x1,  6); x1 ^= x0;
    x0 += k0; x1 += k1 + 3u;

    x0 += x1; x1 = rotl32(x1, 17); x1 ^= x0;
    x0 += x1; x1 = rotl32(x1, 29); x1 ^= x0;
    x0 += x1; x1 = rotl32(x1, 16); x1 ^= x0;
    x0 += x1; x1 = rotl32(x1, 24); x1 ^= x0;
    x0 += k1; x1 += ks2 + 4u;

    x0 += x1; x1 = rotl32(x1, 13); x1 ^= x0;
    x0 += x1; x1 = rotl32(x1, 15); x1 ^= x0;
    x0 += x1; x1 = rotl32(x1, 26); x1 ^= x0;
    x0 += x1; x1 = rotl32(x1,  6); x1 ^= x0;
    x0 += ks2; x1 += k0 + 5u;

    return x0 ^ x1;
}

// u (f64, JAX-exact) and fast f32 L = -log(u).     (verbatim, proven)
__device__ __forceinline__ float fastL(uint32_t bits, double& ud) {
    const double S = 1.0 - 1e-10, T = 1e-10;
    uint32_t fb = (bits >> 9) | 0x3F800000u;
    float bf = __uint_as_float(fb) - 1.0f;            // exact 23-bit uniform [0,1)
    ud = (double)bf * S + T;                          // >= 1e-10 by construction
    if (bf <= 0.5f) {
        return -logf((float)ud);
    } else {
        double vm1 = S * ((double)bf - 1.0);          // u-1 in f64 (no cancel loss)
        return -log1pf((float)vm1);
    }
}

// rare exact-path fallback                          (verbatim, proven)
__device__ __noinline__ bool decide_slow(double a2, double c2,
                                         double u0, double u1) {
    return a2 * (-log(u1)) >= c2 * (-log(u0));
}

// ---------------------------------------------------------------------------
// Prep (R2-R10 proven): zero out (262144 f32 == grid), F = wa*amp+wp*ph (f64,
// ws), A2[j] = A_jj^2.  grid 1024 x 256.
// ---------------------------------------------------------------------------
__global__ void prep_kernel(const float* __restrict__ amp,
                            const float* __restrict__ ph,
                            const float* __restrict__ A,
                            const float* __restrict__ wav,
                            const float* __restrict__ wpv,
                            double* __restrict__ F,
                            double* __restrict__ A2,
                            float* __restrict__ out) {
    int t = blockIdx.x * 256 + threadIdx.x;
    out[t] = 0.0f;
    if (t < NB * NC * NK) {
        double wa = (double)wav[0], wp = (double)wpv[0];
        F[t] = wa * (double)amp[t] + wp * (double)ph[t];
    }
    if (t < NK) {
        double a = (double)A[t * NK + t];
        A2[t] = a * a;
    }
}

// ---------------------------------------------------------------------------
// Fused sample kernel = R7 (best measured) with ONE change: fi values staged
// into LDS once at start (broadcast reads in the hot loop) instead of
// per-iteration scalar s_loads -> no SMEM/lgkmcnt serialization in the loop.
// grid (128, 8) x 256; thread owns cols j = 2*tid, 2*tid+1 for ROWS=4 rows.
// Wave w owns j in [128w, 128w+128); all compaction state WAVE-LOCAL.
// ---------------------------------------------------------------------------
__global__ __launch_bounds__(256) void sample_kernel(
    const double* __restrict__ F, const double* __restrict__ A2,
    float* __restrict__ out)
{
    const int i0   = blockIdx.x * ROWS;
    const int b    = blockIdx.y;
    const int tid  = threadIdx.x;
    const int j0   = 2 * tid;
    const int lane = tid & 63;
    const int wv   = tid >> 6;          // wave index 0..3
    const int wjb  = wv * 128;          // wave's j base

    __shared__ double fi_s[ROWS][NC];               // staged fi, 1 KB
    __shared__ double Dsh[4][ROWS][128];            // wave-private D mirror, 16 KB
    __shared__ unsigned short wlist[4][ROWS * 128]; // fused wave lists, 4 KB
    __shared__ double sred[ROWS][4];
    __shared__ double s_q[ROWS];

    const double* __restrict__ Fb = F + (size_t)b * NC * NK;

    // ---- Phase 0: one-time fi staging (4 consecutive lanes -> 4 consecutive
    // doubles of one F row; 32 B chunks, one gather, never again in the loop)
    if (tid < ROWS * NC) {
        int r = tid & (ROWS - 1);
        int c = tid >> 2;                    // ROWS == 4
        fi_s[r][c] = Fb[c * NK + i0 + r];
    }
    __syncthreads();

    // ---- Phase 1: dist accumulation (same per-element fma chain as R1-R10)
    double acc[2][ROWS];
    #pragma unroll
    for (int it = 0; it < 2; ++it)
        #pragma unroll
        for (int r = 0; r < ROWS; ++r) acc[it][r] = 0.0;

    #pragma unroll 8
    for (int c = 0; c < NC; ++c) {
        double2 fj = *(const double2*)(Fb + c * NK + j0);   // 16B coalesced
        #pragma unroll
        for (int r = 0; r < ROWS; ++r) {
            double fic = fi_s[r][c];         // wave-uniform addr -> broadcast
            double d0 = fic - fj.x; acc[0][r] = fma(d0, d0, acc[0][r]);
            double d1 = fic - fj.y; acc[1][r] = fma(d1, d1, acc[1][r]);
        }
    }

    double2 a2j = *(const double2*)(A2 + j0);
    double D[2][ROWS];
    #pragma unroll
    for (int r = 0; r < ROWS; ++r) {
        D[0][r] = acc[0][r] * a2j.x + 1e-10;   // same rounding as R1-R10
        D[1][r] = acc[1][r] * a2j.y + 1e-10;
        // wave-private mirror for dynamic-(r,jl) access in phase 3
        *(double2*)&Dsh[wv][r][2 * lane] = make_double2(D[0][r], D[1][r]);
    }

    // per-row min over j != i (exact, order-independent; proven path)
    #pragma unroll
    for (int r = 0; r < ROWS; ++r) {
        const int i = i0 + r;
        double m = 1e300;
        if (j0     != i) m = fmin(m, D[0][r]);
        if (j0 + 1 != i) m = fmin(m, D[1][r]);
        #pragma unroll
        for (int off = 32; off > 0; off >>= 1)
            m = fmin(m, __shfl_down(m, off));
        if (lane == 0) sred[r][wv] = m;
    }
    __syncthreads();
    if (tid < ROWS) {
        double m = fmin(fmin(sred[tid][0], sred[tid][1]),
                        fmin(sred[tid][2], sred[tid][3]));
        s_q[tid] = 0.99 * m;
    }
    __syncthreads();

    // ---- Phase 2: stage-1 deterministic-false filter + FUSED wave-local list
    // Skip iff (D-q)^2 > 1.95e8*q^2 (false for ANY draw; 1% log-margin, f64).
    const unsigned long long ltmask = (1ull << lane) - 1ull;
    int nb = 0;                                  // wave-uniform running count
    #pragma unroll
    for (int r = 0; r < ROWS; ++r) {
        const int i = i0 + r;
        const double q = s_q[r];
        const double thr = 1.95e8 * (q * q);
        double t0 = D[0][r] - q;
        double t1 = D[1][r] - q;
        bool need0 = (j0     == i) || !(t0 * t0 > thr);
        bool need1 = (j0 + 1 == i) || !(t1 * t1 > thr);
        unsigned long long m0 = __ballot(need0);
        unsigned long long m1 = __ballot(need1);
        int c0 = __popcll(m0);
        if (need0) wlist[wv][nb + __popcll(m0 & ltmask)] =
            (unsigned short)((r << 8) | (2 * lane));
        if (need1) wlist[wv][nb + c0 + __popcll(m1 & ltmask)] =
            (unsigned short)((r << 8) | (2 * lane + 1));
        nb += c0 + __popcll(m1);
    }
    // same-wave LDS RAW: ordered by program order + lgkmcnt, no barrier needed

    // ---- Phase 3: staged RNG over the fused wave list (R7 verbatim)
    for (int k0v = 0; k0v < nb; k0v += 64) {
        int k = k0v + lane;
        bool act = k < nb;
        int e  = wlist[wv][act ? k : 0];          // in-bounds always
        int r  = e >> 8;
        int jl = e & 255;
        double Dv = Dsh[wv][r][jl];
        double q  = s_q[r];
        const int i = i0 + r;
        const int j = wjb + jl;

        double a2, c2;
        if (j == i) { a2 = 9801.0; c2 = 1.0; }
        else        { a2 = q * q; double t = Dv - q; c2 = t * t; }

        uint32_t n0 = 2u * (((uint32_t)(b * NK + i)) * NK + (uint32_t)j);
        bool hit = false;
        if (act) {
            uint32_t bits0 = jax_random_bits(n0);
            double u0d;
            float L0f = fastL(bits0, u0d);
            float L0lo = L0f * 0.99999f;
            // stage-2 conservative skip: provably false for any u1
            // (L1 <= -ln(1e-10) = 23.0258509...; margin >= 1.5e-4 rel)
            if (!((double)c2 * (double)L0lo > 23.03 * a2)) {
                uint32_t bits1 = jax_random_bits(n0 + 1u);
                double u1d;
                float L1f = fastL(bits1, u1d);
                float lhs = (float)a2 * L1f;
                float rhs = (float)c2 * L0f;
                float diff = lhs - rhs;
                if (fabsf(diff) > 1e-4f * (lhs + rhs))
                    hit = diff >= 0.0f;               // fast path, sign-safe
                else
                    hit = decide_slow(a2, c2, u0d, u1d);
            }
        }
        if (hit)
            atomicAdd(&out[i * NK + j], 0.125f);      // mean over B=8, exact
    }
}

extern "C" void kernel_launch(void* const* d_in, const int* in_sizes, int n_in,
                              void* d_out, int out_size, void* d_ws, size_t ws_size,
                              hipStream_t stream) {
    const float* amp = (const float*)d_in[0];   // (8,32,512)
    const float* ph  = (const float*)d_in[1];   // (8,32,512)
    const float* A   = (const float*)d_in[2];   // (512,512)
    const float* wa  = (const float*)d_in[3];   // scalar
    const float* wp  = (const float*)d_in[4];   // scalar
    float* out = (float*)d_out;                 // (512,512) f32

    double* F  = (double*)d_ws;                    // 131072 f64 = 1 MB
    double* A2 = F + NB * NC * NK;                 // 512 f64

    prep_kernel<<<1024, 256, 0, stream>>>(amp, ph, A, wa, wp, F, A2, out);

    dim3 grid(NK / ROWS, NB);                      // (128, 8) = 1024 blocks
    sample_kernel<<<grid, 256, 0, stream>>>(F, A2, out);
}